// Round 4
// baseline (377.894 us; speedup 1.0000x reference)
//
#include <hip/hip_runtime.h>

typedef unsigned short u16;
typedef u16  u16x8  __attribute__((ext_vector_type(8)));
typedef _Float16 f16x4 __attribute__((ext_vector_type(4)));
typedef _Float16 f16x8 __attribute__((ext_vector_type(8)));
typedef float f32x4 __attribute__((ext_vector_type(4)));

#define HW 4096
#define CIN 256

// ---------------- convert x (fp32->fp16) + channel means; convert W ----------------
__global__ __launch_bounds__(256) void convert_kernel(const float* x1, const float* x2, const float* x3,
        const float* W1, const float* W2, const float* W3,
        _Float16* xh, _Float16* wh, float* mean) {
    int bx = blockIdx.x; int t = threadIdx.x;
    if (bx < 1536) {
        int xi = bx >> 9, b = (bx >> 8) & 1, c = bx & 255;
        const float* src = (xi == 0 ? x1 : xi == 1 ? x2 : x3) + (size_t)(b * CIN + c) * HW;
        _Float16* dst = xh + ((size_t)((xi * 2 + b) * CIN) + c) * HW;
        float s = 0.f;
        for (int i = t; i < 1024; i += 256) {
            f32x4 v = ((const f32x4*)src)[i];
            s += v[0] + v[1] + v[2] + v[3];
            f16x4 h;
#pragma unroll
            for (int r = 0; r < 4; ++r) h[r] = (_Float16)v[r];
            ((f16x4*)dst)[i] = h;
        }
        __shared__ float red[256];
        red[t] = s; __syncthreads();
        for (int k = 128; k; k >>= 1) { if (t < k) red[t] += red[t + k]; __syncthreads(); }
        if (t == 0) mean[(xi * 2 + b) * CIN + c] = red[0] * (1.f / HW);
    } else {
        int j = bx - 1536;                 // 0..5
        int widx = j >> 1, half = j & 1;
        const float* wsrc = (widx == 0 ? W1 : widx == 1 ? W2 : W3) + half * 4096;
        _Float16* wdst = wh + widx * 8192 + half * 4096;
        for (int i = t; i < 1024; i += 256) {
            f32x4 v = ((const f32x4*)wsrc)[i];
            f16x4 h;
#pragma unroll
            for (int r = 0; r < 4; ++r) h[r] = (_Float16)v[r];
            ((f16x4*)wdst)[i] = h;
        }
    }
}

// ---------------- M2[x][b][c1][c2] = E_p[x_c1 x_c2] via f16 MFMA ----------------
__global__ __launch_bounds__(256) void m2_kernel(const _Float16* xh, float* M2) {
    int xi = blockIdx.y, b = blockIdx.z;
    const _Float16* xb = xh + (size_t)(xi * 2 + b) * CIN * HW;
    int t = threadIdx.x; int wv = t >> 6; int L = t & 63; int m = L & 15; int quad = L >> 4;
    int tile = blockIdx.x * 4 + wv;            // 0..255
    int c1t = (tile >> 4) * 16, c2t = (tile & 15) * 16;
    const f16x8* ap = (const f16x8*)(xb + (size_t)(c1t + m) * HW + quad * 8);
    const f16x8* bp = (const f16x8*)(xb + (size_t)(c2t + m) * HW + quad * 8);
    f32x4 a0 = {0,0,0,0}, a1 = {0,0,0,0};
#pragma unroll 4
    for (int p = 0; p < 128; p += 2) {
        a0 = __builtin_amdgcn_mfma_f32_16x16x32_f16(ap[p * 4], bp[p * 4], a0, 0, 0, 0);
        a1 = __builtin_amdgcn_mfma_f32_16x16x32_f16(ap[(p + 1) * 4], bp[(p + 1) * 4], a1, 0, 0, 0);
    }
    f32x4 acc = a0 + a1;
    float* dst = M2 + ((size_t)(xi * 2 + b) * CIN) * CIN;
#pragma unroll
    for (int r = 0; r < 4; ++r)
        dst[(size_t)(c1t + quad * 4 + r) * CIN + c2t + m] = acc[r] * (1.f / HW);
}

// ---------------- per-(x,b,o) affine params from stats ----------------
__global__ __launch_bounds__(256) void stats_kernel(const float* M2, const float* mean,
        const float* W1, const float* W2, const float* W3,
        const float* g1, const float* g2, const float* g3,
        const float* b1, const float* b2, const float* b3, float2* afine) {
    int o = blockIdx.x; int xi = blockIdx.y; int b = blockIdx.z;
    int widx = o >> 5; int oc = o & 31;
    const float* Wp = (widx == 0 ? W1 : widx == 1 ? W2 : W3) + oc * CIN;
    const float* gp = (widx == 0 ? g1 : widx == 1 ? g2 : g3);
    const float* bp = (widx == 0 ? b1 : widx == 1 ? b2 : b3);
    int t = threadIdx.x;
    __shared__ float sW[256];
    __shared__ float red[256];
    sW[t] = Wp[t];
    __syncthreads();
    const float* m2row = M2 + ((size_t)(xi * 2 + b) * CIN + t) * CIN;
    float tv = 0.f;
    const f32x4* r4 = (const f32x4*)m2row;
#pragma unroll 4
    for (int k = 0; k < 64; ++k) {
        f32x4 mv = r4[k];
        const f32x4 wv = *(const f32x4*)&sW[k * 4];
        tv += mv[0] * wv[0] + mv[1] * wv[1] + mv[2] * wv[2] + mv[3] * wv[3];
    }
    red[t] = tv * sW[t]; __syncthreads();
    for (int k = 128; k; k >>= 1) { if (t < k) red[t] += red[t + k]; __syncthreads(); }
    float E2 = red[0]; __syncthreads();
    red[t] = sW[t] * mean[(xi * 2 + b) * CIN + t]; __syncthreads();
    for (int k = 128; k; k >>= 1) { if (t < k) red[t] += red[t + k]; __syncthreads(); }
    if (t == 0) {
        float mu = red[0];
        float var = E2 - mu * mu;
        float rsig = rsqrtf(var + 1e-5f);
        float scale = gp[oc] * rsig;
        afine[(xi * 2 + b) * 96 + o] = make_float2(scale, bp[oc] - mu * scale);
    }
}

// ---- conv + norm + relu: writes qT/kT (fp16, pixel-major) and v (fp32 out) ----
__global__ __launch_bounds__(256) void conv_kernel(const _Float16* xh, const _Float16* wh,
        const float2* afine, _Float16* qT, _Float16* kT, float* out) {
    int xi = blockIdx.y, b = blockIdx.z;
    const u16* xb = (const u16*)(xh + (size_t)(xi * 2 + b) * CIN * HW);
    int p0 = blockIdx.x * 64;
    __shared__ u16 lds[32 * 65 * 8];
    int t = threadIdx.x;
    {   // stage x[256][64] into LDS, transposed to 8-channel cells [cblk][f(p)][8c]
        int pc = t & 7, cg = t >> 3;
        u16x8 a[8];
#pragma unroll
        for (int r = 0; r < 8; ++r)
            a[r] = *(const u16x8*)(xb + (size_t)(cg * 8 + r) * HW + p0 + pc * 8);
#pragma unroll
        for (int i = 0; i < 8; ++i) {
            u16x8 d;
#pragma unroll
            for (int r = 0; r < 8; ++r) d[r] = a[r][i];
            int p = pc * 8 + i; int fp = p ^ (p >> 3);
            *(u16x8*)&lds[(cg * 65 + fp) * 8] = d;
        }
    }
    __syncthreads();
    int wv = t >> 6, L = t & 63, m = L & 15, quad = L >> 4;
    int pw0 = wv * 16;
    f16x8 af[8];
    {
        int p = pw0 + m; int fp = p ^ (p >> 3);
#pragma unroll
        for (int k = 0; k < 8; ++k)
            af[k] = *(const f16x8*)&lds[((k * 4 + quad) * 65 + fp) * 8];
    }
    int xb2 = xi * 2 + b;
    for (int ot = 0; ot < 6; ++ot) {
        int o0 = ot * 16; int widx = ot >> 1;
        int o_col = o0 + m;                         // global output channel 0..95
        f32x4 acc = {0, 0, 0, 0};
#pragma unroll
        for (int k = 0; k < 8; ++k) {
            f16x8 bfr = *(const f16x8*)(wh + (size_t)o_col * CIN + k * 32 + quad * 8);
            acc = __builtin_amdgcn_mfma_f32_16x16x32_f16(af[k], bfr, acc, 0, 0, 0);
        }
        float2 afv = afine[xb2 * 96 + o_col];
        f32x4 vals;
#pragma unroll
        for (int r = 0; r < 4; ++r) {
            float v = acc[r] * afv.x + afv.y;
            vals[r] = v > 0.f ? v : 0.f;
        }
        int prow = p0 + pw0 + quad * 4;
        if (widx < 2) {
            _Float16* dst = (widx == 0 ? qT : kT) + (size_t)xb2 * (HW * 32);
            int cc = (o0 & 31) + m;
#pragma unroll
            for (int r = 0; r < 4; ++r)
                dst[(size_t)(prow + r) * 32 + cc] = (_Float16)vals[r];
        } else {
            float* dst = out + (size_t)(5 + xi) * 262144 + (size_t)b * 131072 + (size_t)(o_col - 64) * HW + prow;
            *(f32x4*)dst = vals;    // fp32 output, 4 consecutive pixels
        }
    }
}

// ---- Z-sweeps (exact row softmax): Mv[mat][b][i]=max_j S_ij, R=1/sum_j exp(S-M) ----
__global__ __launch_bounds__(256) void zsweep_kernel(const _Float16* qT, const _Float16* kT,
        float* R, float* Mv, float2* Wa) {
    const int qxA[5] = {0, 1, 1, 2, 0};   // mats: A12 A21 A23 A32 A13
    const int kxA[5] = {1, 0, 2, 1, 2};
    int mat = blockIdx.y, b = blockIdx.z;
    int qx = qxA[mat], kx = kxA[mat];
    const _Float16* qb = qT + (size_t)(qx * 2 + b) * (HW * 32);
    const _Float16* kb = kT + (size_t)(kx * 2 + b) * (HW * 32);
    int t = threadIdx.x; int wv = t >> 6; int L = t & 63; int m = L & 15; int quad = L >> 4;
    int i0 = (blockIdx.x * 4 + wv) * 16;
    f16x8 a = *(const f16x8*)(qb + (size_t)(i0 + m) * 32 + quad * 8);
    const f16x8* kp = (const f16x8*)(kb + m * 32 + quad * 8);
    f32x4 zero = {0.f, 0.f, 0.f, 0.f};
    // phase 1: row max (S >= 0 since q,k >= 0, so init 0 is exact)
    float mx0 = 0.f, mx1 = 0.f, mx2 = 0.f, mx3 = 0.f;
#pragma unroll 4
    for (int j = 0; j < 256; ++j) {
        f16x8 bf = kp[j * 64];
        f32x4 d = __builtin_amdgcn_mfma_f32_16x16x32_f16(a, bf, zero, 0, 0, 0);
        mx0 = fmaxf(mx0, d[0]); mx1 = fmaxf(mx1, d[1]);
        mx2 = fmaxf(mx2, d[2]); mx3 = fmaxf(mx3, d[3]);
    }
#pragma unroll
    for (int msk = 1; msk <= 8; msk <<= 1) {
        mx0 = fmaxf(mx0, __shfl_xor(mx0, msk)); mx1 = fmaxf(mx1, __shfl_xor(mx1, msk));
        mx2 = fmaxf(mx2, __shfl_xor(mx2, msk)); mx3 = fmaxf(mx3, __shfl_xor(mx3, msk));
    }
    // phase 2: Z with per-row shift (exp arg <= 0, Z >= 1)
    float z0 = 0.f, z1 = 0.f, z2 = 0.f, z3 = 0.f;
#pragma unroll 4
    for (int j = 0; j < 256; ++j) {
        f16x8 bf = kp[j * 64];
        f32x4 d = __builtin_amdgcn_mfma_f32_16x16x32_f16(a, bf, zero, 0, 0, 0);
        z0 += __expf(d[0] - mx0); z1 += __expf(d[1] - mx1);
        z2 += __expf(d[2] - mx2); z3 += __expf(d[3] - mx3);
    }
#pragma unroll
    for (int msk = 1; msk <= 8; msk <<= 1) {
        z0 += __shfl_xor(z0, msk); z1 += __shfl_xor(z1, msk);
        z2 += __shfl_xor(z2, msk); z3 += __shfl_xor(z3, msk);
    }
    if (m == 0) {
        int row = i0 + quad * 4;
        float zz[4] = {z0, z1, z2, z3};
        float mm[4] = {mx0, mx1, mx2, mx3};
#pragma unroll
        for (int r = 0; r < 4; ++r) {
            float rz = 1.0f / zz[r];
            size_t idx = (size_t)(mat * 2 + b) * HW + row + r;
            R[idx] = rz; Mv[idx] = mm[r];
            if (mat == 0 || mat == 4) Wa[idx] = make_float2(rz, 0.f);
        }
    }
}

// ---------------- weighted sweeps: out_j = sum_i w_i * exp(S_ij - M_i) ----------------
struct P2Cfg {
    const _Float16* qb; const _Float16* kb;
    const float* Mv;                 // row maxes for this mat (2 batches)
    const float2* wt;
    float* o1; float* o2;
    const float* rn; const float* aux; float2* wn;
    int wtype;   // -1: none, 0: {rn, o1*rn}, 1: {o1*rn, o2*rn}, 2: {o2*rn, aux*rn}
};

__global__ __launch_bounds__(512) void pass2_kernel(P2Cfg c0, P2Cfg c1) {
    P2Cfg c = (blockIdx.y == 0) ? c0 : c1;
    int b = blockIdx.z;
    const _Float16* qb = c.qb + (size_t)b * (HW * 32);
    const _Float16* kb = c.kb + (size_t)b * (HW * 32);
    const float2* wt = c.wt + (size_t)b * HW;
    const float* Mb = c.Mv + (size_t)b * HW;
    int t = threadIdx.x; int wv = t >> 6; int L = t & 63; int m = L & 15; int quad = L >> 4;
    int j0 = blockIdx.x * 16;
    f16x8 bf = *(const f16x8*)(kb + (size_t)(j0 + m) * 32 + quad * 8);
    f32x4 zero = {0.f, 0.f, 0.f, 0.f};
    float a1 = 0.f, a2 = 0.f;
    int ib = wv * 512;
#pragma unroll 2
    for (int tt = 0; tt < 32; ++tt) {
        int i0 = ib + tt * 16;
        f16x8 a = *(const f16x8*)(qb + (size_t)(i0 + m) * 32 + quad * 8);
        f32x4 d = __builtin_amdgcn_mfma_f32_16x16x32_f16(a, bf, zero, 0, 0, 0);
        const float2* wr = wt + i0 + quad * 4;
        f32x4 Mr = *(const f32x4*)(Mb + i0 + quad * 4);
#pragma unroll
        for (int r = 0; r < 4; ++r) {
            float e = __expf(d[r] - Mr[r]);
            float2 w = wr[r];
            a1 += e * w.x; a2 += e * w.y;
        }
    }
    a1 += __shfl_xor(a1, 16); a1 += __shfl_xor(a1, 32);
    a2 += __shfl_xor(a2, 16); a2 += __shfl_xor(a2, 32);
    __shared__ float2 red[8][16];
    if (L < 16) red[wv][L] = make_float2(a1, a2);
    __syncthreads();
    if (t < 16) {
        float s1 = 0.f, s2 = 0.f;
#pragma unroll
        for (int w = 0; w < 8; ++w) { s1 += red[w][t].x; s2 += red[w][t].y; }
        int jo = b * HW + j0 + t;
        c.o1[jo] = s1; c.o2[jo] = s2;
        if (c.wtype >= 0) {
            float rn = c.rn[jo]; float2 wn;
            if (c.wtype == 0)      wn = make_float2(rn, s1 * rn);
            else if (c.wtype == 1) wn = make_float2(s1 * rn, s2 * rn);
            else                   wn = make_float2(s2 * rn, c.aux[jo] * rn);
            c.wn[jo] = wn;
        }
    }
}

// ---------------- broadcast 5 [b,hw] vectors to fp32 [b,32,hw] outputs ----------------
__global__ __launch_bounds__(256) void bcast_kernel(const float* vecs, float* out) {
    int bx = blockIdx.x;              // 0..319
    int s = bx >> 6; int rem = bx & 63; int b = rem >> 5; int c = rem & 31;
    const int vidx[5] = {6, 7, 4, 2, 5};  // p1a, p1b, p2, p3a(u), p3b(c13)
    const float* src = vecs + (size_t)(vidx[s] * 2 + b) * HW;
    float* dst = out + ((size_t)(s * 2 + b) * 32 + c) * HW;
    int t = threadIdx.x;
#pragma unroll
    for (int k = 0; k < 4; ++k)
        ((f32x4*)dst)[k * 256 + t] = ((const f32x4*)src)[k * 256 + t];
}

extern "C" void kernel_launch(void* const* d_in, const int* in_sizes, int n_in,
                              void* d_out, int out_size, void* d_ws, size_t ws_size,
                              hipStream_t stream) {
    (void)in_sizes; (void)n_in; (void)out_size; (void)ws_size;
    const float* x1 = (const float*)d_in[0];
    const float* x2 = (const float*)d_in[1];
    const float* x3 = (const float*)d_in[2];
    const float* W1 = (const float*)d_in[3];
    const float* g1 = (const float*)d_in[4];
    const float* b1 = (const float*)d_in[5];
    const float* W2 = (const float*)d_in[6];
    const float* g2 = (const float*)d_in[7];
    const float* b2 = (const float*)d_in[8];
    const float* W3 = (const float*)d_in[9];
    const float* g3 = (const float*)d_in[10];
    const float* b3 = (const float*)d_in[11];
    float* out = (float*)d_out;      // reference outputs are float32

    char* w = (char*)d_ws;
    _Float16* xh    = (_Float16*)(w);                    // 12,582,912 B
    _Float16* wh    = (_Float16*)(w + 12582912);         //    49,152 B
    float*    mean  = (float*)(w + 12632064);            //     6,144 B
    float*    M2    = (float*)(w + 12638208);            // 1,572,864 B
    float2*   afine = (float2*)(w + 14211072);           //     4,608 B
    _Float16* qT    = (_Float16*)(w + 14215680);         // 1,572,864 B
    _Float16* kT    = (_Float16*)(w + 15788544);         // 1,572,864 B
    float*    R     = (float*)(w + 17361408);            //   163,840 B
    float*    Mv    = (float*)(w + 17525248);            //   163,840 B
    float2*   Wa    = (float2*)(w + 17689088);           //   327,680 B
    float*    vecs  = (float*)(w + 18016768);            //   294,912 B

    float* v_c12 = vecs + 0 * 8192;
    float* v_c23 = vecs + 1 * 8192;
    float* v_u   = vecs + 2 * 8192;   // p3a
    float* v_w1  = vecs + 3 * 8192;
    float* v_p2  = vecs + 4 * 8192;
    float* v_p3b = vecs + 5 * 8192;
    float* v_p1a = vecs + 6 * 8192;
    float* v_p1b = vecs + 7 * 8192;
    float* v_dmy = vecs + 8 * 8192;

    hipLaunchKernelGGL(convert_kernel, dim3(1542), dim3(256), 0, stream,
                       x1, x2, x3, W1, W2, W3, xh, wh, mean);
    hipLaunchKernelGGL(m2_kernel, dim3(64, 3, 2), dim3(256), 0, stream, xh, M2);
    hipLaunchKernelGGL(stats_kernel, dim3(96, 3, 2), dim3(256), 0, stream,
                       M2, mean, W1, W2, W3, g1, g2, g3, b1, b2, b3, afine);
    hipLaunchKernelGGL(conv_kernel, dim3(64, 3, 2), dim3(256), 0, stream,
                       xh, wh, afine, qT, kT, out);
    hipLaunchKernelGGL(zsweep_kernel, dim3(64, 5, 2), dim3(256), 0, stream, qT, kT, R, Mv, Wa);

    // mats: 0:A12(q1,k2) 1:A21(q2,k1) 2:A23(q2,k3) 3:A32(q3,k2) 4:A13(q1,k3)
    P2Cfg cA0 = { qT + 0 * 2 * (HW * 32), kT + 1 * 2 * (HW * 32), Mv + 0 * 2 * HW,
                  Wa + 0 * 8192, v_c12, v_dmy, R + 2 * 8192, nullptr, Wa + 2 * 8192, 0 };
    P2Cfg cA1 = { qT + 0 * 2 * (HW * 32), kT + 2 * 2 * (HW * 32), Mv + 4 * 2 * HW,
                  Wa + 4 * 8192, v_p3b, v_dmy, nullptr, nullptr, nullptr, -1 };
    hipLaunchKernelGGL(pass2_kernel, dim3(256, 2, 2), dim3(512), 0, stream, cA0, cA1);

    P2Cfg cB = { qT + 1 * 2 * (HW * 32), kT + 2 * 2 * (HW * 32), Mv + 2 * 2 * HW,
                 Wa + 2 * 8192, v_c23, v_u, R + 3 * 8192, nullptr, Wa + 3 * 8192, 1 };
    hipLaunchKernelGGL(pass2_kernel, dim3(256, 1, 2), dim3(512), 0, stream, cB, cB);

    P2Cfg cC = { qT + 2 * 2 * (HW * 32), kT + 1 * 2 * (HW * 32), Mv + 3 * 2 * HW,
                 Wa + 3 * 8192, v_p2, v_w1, R + 1 * 8192, v_c12, Wa + 1 * 8192, 2 };
    hipLaunchKernelGGL(pass2_kernel, dim3(256, 1, 2), dim3(512), 0, stream, cC, cC);

    P2Cfg cD = { qT + 1 * 2 * (HW * 32), kT + 0 * 2 * (HW * 32), Mv + 1 * 2 * HW,
                 Wa + 1 * 8192, v_p1a, v_p1b, nullptr, nullptr, nullptr, -1 };
    hipLaunchKernelGGL(pass2_kernel, dim3(256, 1, 2), dim3(512), 0, stream, cD, cD);

    hipLaunchKernelGGL(bcast_kernel, dim3(320), dim3(256), 0, stream, vecs, out);
}